// Round 9
// baseline (139.520 us; speedup 1.0000x reference)
//
#include <hip/hip_runtime.h>
#include <hip/hip_bf16.h>

// Problem constants: B=8, L=1024, D=1024, H=16, K=64
// Reference (bug reproduced): no softmax => linear attention:
//   out_b = Q_b @ U_b + b_out,  U_b[h*64+j, n] = sum_k S_bh[j,k] w_out[h*64+k, n],
//   S_bh = K_h^T V_h / 8.

typedef __attribute__((ext_vector_type(8))) short short8;
typedef __attribute__((ext_vector_type(4))) float f32x4;

static __device__ __forceinline__ short f2bf(float f) {
  __hip_bfloat16 h = __float2bfloat16(f);
  return __builtin_bit_cast(short, h);
}
static __device__ __forceinline__ float bf2f(short s) {
  unsigned int u = ((unsigned int)(unsigned short)s) << 16;
  return __builtin_bit_cast(float, u);
}

#define GLOAD16(src, dst)                                        \
  __builtin_amdgcn_global_load_lds(                              \
      (const __attribute__((address_space(1))) void*)(src),      \
      (__attribute__((address_space(3))) void*)(dst), 16, 0, 0)
#define BAR() __builtin_amdgcn_s_barrier()
#define SCHED() __builtin_amdgcn_sched_barrier(0)
#define WAIT_VM4() asm volatile("s_waitcnt vmcnt(4)" ::: "memory")
#define WAIT_VM2() asm volatile("s_waitcnt vmcnt(2)" ::: "memory")
#define WAIT_VM0() asm volatile("s_waitcnt vmcnt(0)" ::: "memory")
#define WAIT_LGKM0() asm volatile("s_waitcnt lgkmcnt(0)" ::: "memory")

// ---------------- prep: transpose + cast w_in / w_out (weights only) -----
static __device__ __forceinline__ void transpose_body(
    const float* __restrict__ in, __hip_bfloat16* __restrict__ out,
    int R, int C, int c0, int r0, float tile[32][33]) {
  int tx = threadIdx.x & 31;
  int ty = threadIdx.x >> 5;  // 0..7
#pragma unroll
  for (int i = 0; i < 4; ++i)
    tile[ty + i * 8][tx] = in[(size_t)(r0 + ty + i * 8) * C + c0 + tx];
  __syncthreads();
#pragma unroll
  for (int i = 0; i < 4; ++i)
    out[(size_t)(c0 + ty + i * 8) * R + r0 + tx] =
        __float2bfloat16(tile[tx][ty + i * 8]);
}

__global__ __launch_bounds__(256) void prep_kernel(
    const float* __restrict__ w_in, __hip_bfloat16* __restrict__ w_inT,
    const float* __restrict__ w_out, __hip_bfloat16* __restrict__ w_outT) {
  __shared__ float tile[32][33];
  const int bx = blockIdx.x;
  if (bx < 3072) {  // w_in: 1024 x 3072 -> 96 x 32 tiles
    transpose_body(w_in, w_inT, 1024, 3072, (bx % 96) * 32, (bx / 96) * 32, tile);
  } else {          // w_out: 1024 x 1024 -> 32 x 32 tiles
    int b = bx - 3072;
    transpose_body(w_out, w_outT, 1024, 1024, (b % 32) * 32, (b / 32) * 32, tile);
  }
}

// ---------------- bf16 MFMA GEMM v4: 3-buf counted-vmcnt + T2 swizzle ----
// C(..xNOUT) = A(stride AS, dtype AT) @ Bt(NxKD)^T + bias.  128x128 tile,
// BK=32, 4 waves (2x2), each wave 64x64 = 4x4 frags of 16x16x32.
// B staged via global_load_lds (linear LDS dest, source pre-permuted).
// A: if AT==float, T14 reg-staged (load fp32 top of step, cvt+ds_write at
// bottom) -- removes the separate x->bf16 cast kernel; else gload_lds.
// Pipeline: stage buf k+2 at top of step k; counted vmcnt at bottom keeps
// this step's B loads in flight across the barrier.  LDS [128][32] bf16,
// kg' = kg ^ ((row>>1)&3) XOR swizzle (conflict-free, verified R8).
static __device__ __forceinline__ void store_out(__hip_bfloat16* p, float v) {
  *p = __float2bfloat16(v);
}
static __device__ __forceinline__ void store_out(float* p, float v) { *p = v; }

template <typename OutT, typename AT, int KD, int AS, int NBN, int NOUT, long BTB>
__global__ __launch_bounds__(256) void gemm_bt_kernel(
    const AT* __restrict__ A, const __hip_bfloat16* __restrict__ Bt,
    const float* __restrict__ bias, OutT* __restrict__ C) {
  constexpr bool A_F32 = (sizeof(AT) == 4);
  __shared__ __align__(16) __hip_bfloat16 As[3][128 * 32];
  __shared__ __align__(16) __hip_bfloat16 Bs[3][128 * 32];

  const int t = threadIdx.x;
  A += (size_t)blockIdx.y * 1024 * AS;
  Bt += (size_t)blockIdx.y * BTB;
  C += (size_t)blockIdx.y * 1024 * NOUT;

  // XCD swizzle (gridDim.x % 8 == 0). For GEMM1 (NBN==24): 4x4 supertiles
  // within the chunk (working set ~2MB < 4MB per-XCD L2).
  const int xcd = blockIdx.x & 7;
  const int c = blockIdx.x >> 3;  // [0, cpx)
  int bm, bn;
  if constexpr (NBN == 24) {
    const int st = c >> 4;          // 0..11 supertiles (2 rows x 6 cols)
    const int im = (c >> 2) & 3, in_ = c & 3;
    bm = xcd * 8 + (st & 1) * 4 + im;
    bn = (st >> 1) * 4 + in_;
  } else {
    const int cpx = gridDim.x >> 3;
    const int wg = xcd * cpx + c;
    bm = wg / NBN; bn = wg % NBN;
  }
  const int m0 = bm * 128, n0 = bn * 128;

  const int w = t >> 6, lane = t & 63;
  const int wr = w >> 1, wc = w & 1;
  const int lr = lane & 15, kg = lane >> 4;

  // staging granules (8 bf16 / 8 fp32 source values = one 16B LDS slot);
  // tile = 512 granules; wave w covers [w*128, +128).  LDS slot (row, j)
  // holds global (row, j ^ sw(row)), sw(row) = (row>>1)&3.
  const int g0 = w * 128 + lane;
  const int g1 = g0 + 64;
  const int r0g = g0 >> 2, j0g = (g0 & 3) ^ ((r0g >> 1) & 3);
  const int r1g = g1 >> 2, j1g = (g1 & 3) ^ ((r1g >> 1) & 3);
  const AT* srcA0 = A + (size_t)(m0 + r0g) * AS + j0g * 8;
  const AT* srcA1 = A + (size_t)(m0 + r1g) * AS + j1g * 8;
  const __hip_bfloat16* srcB0 = Bt + (size_t)(n0 + r0g) * KD + j0g * 8;
  const __hip_bfloat16* srcB1 = Bt + (size_t)(n0 + r1g) * KD + j1g * 8;
  const int lds0 = w * 128 * 8;        // element offset of wave's region
  const int lds1 = (w * 128 + 64) * 8;

  f32x4 acc[4][4] = {};
  constexpr int steps = KD / 32;

  auto stageB = [&](int buf, int kt) {
    const int ko = kt * 32;
    GLOAD16(srcB0 + ko, &Bs[buf][lds0]);
    GLOAD16(srcB1 + ko, &Bs[buf][lds1]);
  };
  // fp32 A path: load 8 floats per granule into regs
  float4 a0lo, a0hi, a1lo, a1hi;
  auto loadA = [&](int kt) {
    if constexpr (A_F32) {
      const float* p0 = srcA0 + kt * 32;
      const float* p1 = srcA1 + kt * 32;
      a0lo = *(const float4*)p0; a0hi = *(const float4*)(p0 + 4);
      a1lo = *(const float4*)p1; a1hi = *(const float4*)(p1 + 4);
    }
  };
  auto writeA = [&](int buf) {
    if constexpr (A_F32) {
      short8 o0, o1;
      o0[0] = f2bf(a0lo.x); o0[1] = f2bf(a0lo.y); o0[2] = f2bf(a0lo.z);
      o0[3] = f2bf(a0lo.w); o0[4] = f2bf(a0hi.x); o0[5] = f2bf(a0hi.y);
      o0[6] = f2bf(a0hi.z); o0[7] = f2bf(a0hi.w);
      o1[0] = f2bf(a1lo.x); o1[1] = f2bf(a1lo.y); o1[2] = f2bf(a1lo.z);
      o1[3] = f2bf(a1lo.w); o1[4] = f2bf(a1hi.x); o1[5] = f2bf(a1hi.y);
      o1[6] = f2bf(a1hi.z); o1[7] = f2bf(a1hi.w);
      *(short8*)&As[buf][g0 * 8] = o0;
      *(short8*)&As[buf][g1 * 8] = o1;
    }
  };
  auto stageA_lds = [&](int buf, int kt) {
    if constexpr (!A_F32) {
      const int ko = kt * 32;
      GLOAD16(srcA0 + ko, &As[buf][lds0]);
      GLOAD16(srcA1 + ko, &As[buf][lds1]);
    }
  };

  // fragment read offsets (swizzled): row*32 + (kg ^ ((row>>1)&3))*8
  int offA[4], offB[4];
#pragma unroll
  for (int i = 0; i < 4; ++i) {
    int rowA = wr * 64 + i * 16 + lr;
    int rowB = wc * 64 + i * 16 + lr;
    offA[i] = rowA * 32 + (kg ^ ((rowA >> 1) & 3)) * 8;
    offB[i] = rowB * 32 + (kg ^ ((rowB >> 1) & 3)) * 8;
  }

  // ---- prologue: bufs 0,1 ----
  if constexpr (A_F32) {
    // issue A0 regs, B0 gload, A1 regs, B1 gload; vmcnt(2) leaves B1
    loadA(0);
    stageB(0, 0);
    float4 b0lo = a0lo, b0hi = a0hi, b1lo = a1lo, b1hi = a1hi;  // keep tile0
    loadA(1);
    stageB(1, 1);
    SCHED();
    WAIT_VM2();
    SCHED();
    // write tile1 (current regs) then restore tile0 and write it
    writeA(1);
    a0lo = b0lo; a0hi = b0hi; a1lo = b1lo; a1hi = b1hi;
    writeA(0);
    WAIT_LGKM0();
    SCHED();
    BAR();
    SCHED();
  } else {
    stageA_lds(0, 0); stageB(0, 0);
    stageA_lds(1, 1); stageB(1, 1);
    SCHED();
    WAIT_VM4();  // tile0's 4 loads retired; tile1 in flight
    BAR();
    SCHED();
  }

  int cur = 0;
#pragma unroll 1
  for (int kt = 0; kt < steps; ++kt) {
    int nb = cur + 2; if (nb >= 3) nb -= 3;
    const bool pf = (kt + 2 < steps);
    if (pf) {
      if constexpr (A_F32) loadA(kt + 2);
      else stageA_lds(nb, kt + 2);
      stageB(nb, kt + 2);
    }
    SCHED();
    const __hip_bfloat16* Ac = As[cur];
    const __hip_bfloat16* Bc = Bs[cur];
    short8 af[4], bfv[4];
#pragma unroll
    for (int mi = 0; mi < 4; ++mi) af[mi] = *(const short8*)&Ac[offA[mi]];
#pragma unroll
    for (int ni = 0; ni < 4; ++ni) bfv[ni] = *(const short8*)&Bc[offB[ni]];
#pragma unroll
    for (int mi = 0; mi < 4; ++mi)
#pragma unroll
      for (int ni = 0; ni < 4; ++ni)
        acc[mi][ni] = __builtin_amdgcn_mfma_f32_16x16x32_bf16(
            af[mi], bfv[ni], acc[mi][ni], 0, 0, 0);
    SCHED();
    if constexpr (A_F32) {
      if (pf) {
        WAIT_VM2();  // A regs ready; older B drained; leaves this step's 2 B
        SCHED();
        writeA(nb);
        WAIT_LGKM0();
        SCHED();
      } else {
        WAIT_VM0();
        WAIT_LGKM0();
        SCHED();
      }
    } else {
      if (pf) WAIT_VM4(); else WAIT_VM0();
    }
    BAR();
    SCHED();
    ++cur; if (cur == 3) cur = 0;
  }

  // C/D layout (m89-verified): col = lane&15, row = (lane>>4)*4 + reg
#pragma unroll
  for (int mi = 0; mi < 4; ++mi) {
    int row0 = m0 + wr * 64 + mi * 16 + kg * 4;
#pragma unroll
    for (int ni = 0; ni < 4; ++ni) {
      int col = n0 + wc * 64 + ni * 16 + lr;
      float bv = bias[col];
#pragma unroll
      for (int r = 0; r < 4; ++r)
        store_out(&C[(size_t)(row0 + r) * NOUT + col], acc[mi][ni][r] + bv);
    }
  }
}

// ---------------- Spart[c][b,h] = K_h^T @ V_h over 128 L-rows ------------
__global__ __launch_bounds__(256) void ktv_kernel(
    const __hip_bfloat16* __restrict__ qkv, float* __restrict__ Spart) {
  __shared__ __align__(16) float Ks[64][68];
  __shared__ __align__(16) float Vs[64][68];
  const int bh = blockIdx.x;                 // 0..127
  const int ch = blockIdx.y;                 // 0..7
  const int b = bh >> 4, h = bh & 15;
  const __hip_bfloat16* base = qkv + (size_t)b * 1024 * 3072;
  const int hoff = h * 64;
  const int t = threadIdx.x;
  const int i0 = (t >> 4) * 4;
  const int j0 = (t & 15) * 4;
  const int srow = t >> 2;
  const int sg0 = t & 3;

  f32x4 acc[4] = {};

  for (int c = 0; c < 2; ++c) {
    int l0 = ch * 128 + c * 64;
#pragma unroll
    for (int rep = 0; rep < 2; ++rep) {
      int g = sg0 + rep * 4;
      const __hip_bfloat16* rowp = base + (size_t)(l0 + srow) * 3072;
      short8 kv = *(const short8*)(rowp + 1024 + hoff + g * 8);
      short8 vv = *(const short8*)(rowp + 2048 + hoff + g * 8);
      f32x4 k0, k1, v0, v1;
#pragma unroll
      for (int e = 0; e < 4; ++e) {
        k0[e] = bf2f(kv[e]); k1[e] = bf2f(kv[4 + e]);
        v0[e] = bf2f(vv[e]); v1[e] = bf2f(vv[4 + e]);
      }
      *(f32x4*)&Ks[srow][g * 8] = k0;
      *(f32x4*)&Ks[srow][g * 8 + 4] = k1;
      *(f32x4*)&Vs[srow][g * 8] = v0;
      *(f32x4*)&Vs[srow][g * 8 + 4] = v1;
    }
    __syncthreads();
#pragma unroll 8
    for (int l = 0; l < 64; ++l) {
      f32x4 kq = *(const f32x4*)&Ks[l][i0];
      f32x4 vq = *(const f32x4*)&Vs[l][j0];
#pragma unroll
      for (int ii = 0; ii < 4; ++ii) acc[ii] += kq[ii] * vq;
    }
    __syncthreads();
  }

  float* Sp = Spart + ((size_t)ch * 128 + bh) * 4096;
#pragma unroll
  for (int ii = 0; ii < 4; ++ii)
#pragma unroll
    for (int jj = 0; jj < 4; ++jj)
      Sp[(i0 + ii) * 64 + j0 + jj] = acc[ii][jj];
}

// ---------------- Ut_b[n][h*64+j] = sum_k (S_bh[j][k]/8) w_outT[n][h*64+k]
// grid (128 bh, 2 n-halves) x 256 thr (4 waves, 128 n-rows each).
__global__ __launch_bounds__(256) void ut_kernel(
    const float* __restrict__ Spart, const __hip_bfloat16* __restrict__ w_outT,
    __hip_bfloat16* __restrict__ Ut) {
  __shared__ __align__(16) __hip_bfloat16 Sl[64][72];  // +8 pad
  const int bh = blockIdx.x;
  const int b = bh >> 4, h = bh & 15;
  const int t = threadIdx.x, w = t >> 6, lane = t & 63;
  const int lr = lane & 15, kg = lane >> 4;
  const int nbase = blockIdx.y * 512 + w * 128;

  // stage S_bh: sum 8 partials, scale 1/8, cast bf16
#pragma unroll
  for (int rep = 0; rep < 4; ++rep) {
    int e4 = t + rep * 256;          // f32x4 granule 0..1023
    int row = e4 >> 4, c4 = e4 & 15;
    f32x4 s = {};
#pragma unroll
    for (int c = 0; c < 8; ++c)
      s += *(const f32x4*)&Spart[((size_t)c * 128 + bh) * 4096 + row * 64 + c4 * 4];
    s *= 0.125f;
    __hip_bfloat16* p = &Sl[row][c4 * 4];
    p[0] = __float2bfloat16(s[0]); p[1] = __float2bfloat16(s[1]);
    p[2] = __float2bfloat16(s[2]); p[3] = __float2bfloat16(s[3]);
  }
  __syncthreads();

  const __hip_bfloat16* Ap = w_outT + (size_t)(nbase + lr) * 1024 + h * 64 + kg * 8;
  short8 bF[4][2];
#pragma unroll
  for (int ni = 0; ni < 4; ++ni)
#pragma unroll
    for (int kk = 0; kk < 2; ++kk)
      bF[ni][kk] = *(const short8*)&Sl[ni * 16 + lr][kk * 32 + kg * 8];

  f32x4 acc[8][4] = {};
#pragma unroll
  for (int mi = 0; mi < 8; ++mi) {
#pragma unroll
    for (int kk = 0; kk < 2; ++kk) {
      short8 aF = *(const short8*)(Ap + (size_t)mi * 16 * 1024 + kk * 32);
#pragma unroll
      for (int ni = 0; ni < 4; ++ni)
        acc[mi][ni] = __builtin_amdgcn_mfma_f32_16x16x32_bf16(
            aF, bF[ni][kk], acc[mi][ni], 0, 0, 0);
    }
  }

  __hip_bfloat16* Up = Ut + (size_t)b * 1024 * 1024;
#pragma unroll
  for (int mi = 0; mi < 8; ++mi) {
    int row0 = nbase + mi * 16 + kg * 4;
#pragma unroll
    for (int ni = 0; ni < 4; ++ni) {
      int col = h * 64 + ni * 16 + lr;
#pragma unroll
      for (int r = 0; r < 4; ++r)
        Up[(size_t)(row0 + r) * 1024 + col] = __float2bfloat16(acc[mi][ni][r]);
    }
  }
}

extern "C" void kernel_launch(void* const* d_in, const int* in_sizes, int n_in,
                              void* d_out, int out_size, void* d_ws, size_t ws_size,
                              hipStream_t stream) {
  const float* x = (const float*)d_in[0];
  const float* w_in = (const float*)d_in[1];
  const float* b_in = (const float*)d_in[2];
  const float* w_out = (const float*)d_in[3];
  const float* b_out = (const float*)d_in[4];
  float* out = (float*)d_out;

  char* ws = (char*)d_ws;
  __hip_bfloat16* w_inT = (__hip_bfloat16*)ws;  ws += (size_t)3072 * 1024 * 2;
  __hip_bfloat16* w_outT = (__hip_bfloat16*)ws; ws += (size_t)1024 * 1024 * 2;
  __hip_bfloat16* qkv = (__hip_bfloat16*)ws;    ws += (size_t)8192 * 3072 * 2;
  float* Spart = (float*)ws;                    ws += (size_t)8 * 128 * 64 * 64 * 4;
  __hip_bfloat16* Ut = (__hip_bfloat16*)ws;     ws += (size_t)8 * 1024 * 1024 * 2;

  // prep: transpose w_in (3072 blocks) + w_out (1024 blocks)
  prep_kernel<<<4096, 256, 0, stream>>>(w_in, w_inT, w_out, w_outT);

  // GEMM1: qkv = x @ w_in + b_in  (8192 x 3072, KD=1024), A = fp32 x direct
  gemm_bt_kernel<__hip_bfloat16, float, 1024, 1024, 24, 3072, 0>
      <<<dim3(1536, 1), 256, 0, stream>>>(x, w_inT, b_in, qkv);

  // S partials = Kt V per (b,h) over 128-row chunks
  ktv_kernel<<<dim3(128, 8), 256, 0, stream>>>(qkv, Spart);

  // Ut_b = (S_bh/8 @ Wout_h)^T stacked  -> bf16 (8 x 1024 x 1024)
  ut_kernel<<<dim3(128, 2), 256, 0, stream>>>(Spart, w_outT, Ut);

  // GEMM4': out_b = Q_b @ U_b + b_out  (8 batched 1024x1024, A stride 3072,
  //         Bt batch stride 1024*1024)
  gemm_bt_kernel<float, __hip_bfloat16, 1024, 3072, 8, 1024, 1024 * 1024>
      <<<dim3(64, 8), 256, 0, stream>>>(qkv, Ut, b_out, out);
}

// Round 10
// 137.577 us; speedup vs baseline: 1.0141x; 1.0141x over previous
//
#include <hip/hip_runtime.h>
#include <hip/hip_bf16.h>

// Problem constants: B=8, L=1024, D=1024, H=16, K=64
// Reference (bug reproduced): no softmax => linear attention:
//   out_b = Q_b @ U_b + b_out,  U_b[h*64+j, n] = sum_k S_bh[j,k] w_out[h*64+k, n],
//   S_bh = K_h^T V_h / 8.

typedef __attribute__((ext_vector_type(8))) short short8;
typedef __attribute__((ext_vector_type(4))) float f32x4;

static __device__ __forceinline__ short f2bf(float f) {
  __hip_bfloat16 h = __float2bfloat16(f);
  return __builtin_bit_cast(short, h);
}
static __device__ __forceinline__ float bf2f(short s) {
  unsigned int u = ((unsigned int)(unsigned short)s) << 16;
  return __builtin_bit_cast(float, u);
}

#define GLOAD16(src, dst)                                        \
  __builtin_amdgcn_global_load_lds(                              \
      (const __attribute__((address_space(1))) void*)(src),      \
      (__attribute__((address_space(3))) void*)(dst), 16, 0, 0)
#define BAR() __builtin_amdgcn_s_barrier()
#define SCHED() __builtin_amdgcn_sched_barrier(0)
#define WAIT_VM4() asm volatile("s_waitcnt vmcnt(4)" ::: "memory")
#define WAIT_VM0() asm volatile("s_waitcnt vmcnt(0)" ::: "memory")

// ---------------- fused prep: cast x -> bf16, transpose w_in / w_out -----
static __device__ __forceinline__ void transpose_body(
    const float* __restrict__ in, __hip_bfloat16* __restrict__ out,
    int R, int C, int c0, int r0, float tile[32][33]) {
  int tx = threadIdx.x & 31;
  int ty = threadIdx.x >> 5;  // 0..7
#pragma unroll
  for (int i = 0; i < 4; ++i)
    tile[ty + i * 8][tx] = in[(size_t)(r0 + ty + i * 8) * C + c0 + tx];
  __syncthreads();
#pragma unroll
  for (int i = 0; i < 4; ++i)
    out[(size_t)(c0 + ty + i * 8) * R + r0 + tx] =
        __float2bfloat16(tile[tx][ty + i * 8]);
}

__global__ __launch_bounds__(256) void prep_kernel(
    const float* __restrict__ x, __hip_bfloat16* __restrict__ x_bf,
    const float* __restrict__ w_in, __hip_bfloat16* __restrict__ w_inT,
    const float* __restrict__ w_out, __hip_bfloat16* __restrict__ w_outT) {
  __shared__ float tile[32][33];
  const int bx = blockIdx.x;
  if (bx < 4096) {
    size_t i = ((size_t)bx * 256 + threadIdx.x) * 8;
    float4 v0 = *(const float4*)(x + i);
    float4 v1 = *(const float4*)(x + i + 4);
    short8 o;
    o[0] = f2bf(v0.x); o[1] = f2bf(v0.y); o[2] = f2bf(v0.z); o[3] = f2bf(v0.w);
    o[4] = f2bf(v1.x); o[5] = f2bf(v1.y); o[6] = f2bf(v1.z); o[7] = f2bf(v1.w);
    *(short8*)((__hip_bfloat16*)x_bf + i) = o;
  } else if (bx < 4096 + 3072) {
    int b = bx - 4096;  // w_in: 1024 x 3072 -> 96 x 32 tiles
    transpose_body(w_in, w_inT, 1024, 3072, (b % 96) * 32, (b / 96) * 32, tile);
  } else {
    int b = bx - 7168;  // w_out: 1024 x 1024 -> 32 x 32 tiles
    transpose_body(w_out, w_outT, 1024, 1024, (b % 32) * 32, (b / 32) * 32, tile);
  }
}

// ---------------- bf16 MFMA GEMM (R8-best): 3-buf counted-vmcnt + T2 -----
// C(..xNOUT) = A(stride AS) @ Bt(NxKD)^T + bias.  128x128 tile, BK=32,
// 4 waves (2x2), each wave 64x64 = 4x4 frags of 16x16x32.
// Pipeline: stage tile k+2 at top of step k; s_waitcnt vmcnt(4) (tile k+1
// may stay in flight) + raw s_barrier per step.  LDS [128][32] bf16 with
// kg' = kg ^ ((row>>1)&3) XOR swizzle (bank-conflict-free, verified R8:
// SQ_LDS_BANK_CONFLICT == 0); global_load_lds dest linear, SOURCE
// inverse-permuted (m173 / rule #21).  GEMM1 (NBN==24) uses 4x4 supertile
// ordering within each XCD chunk (FETCH 57->41 MB verified R8).
static __device__ __forceinline__ void store_out(__hip_bfloat16* p, float v) {
  *p = __float2bfloat16(v);
}
static __device__ __forceinline__ void store_out(float* p, float v) { *p = v; }

template <typename OutT, int KD, int AS, int NBN, int NOUT, long BTB>
__global__ __launch_bounds__(256) void gemm_bt_kernel(
    const __hip_bfloat16* __restrict__ A, const __hip_bfloat16* __restrict__ Bt,
    const float* __restrict__ bias, OutT* __restrict__ C) {
  __shared__ __align__(16) __hip_bfloat16 As[3][128 * 32];
  __shared__ __align__(16) __hip_bfloat16 Bs[3][128 * 32];

  const int t = threadIdx.x;
  A += (size_t)blockIdx.y * 1024 * AS;
  Bt += (size_t)blockIdx.y * BTB;
  C += (size_t)blockIdx.y * 1024 * NOUT;

  // XCD swizzle (gridDim.x % 8 == 0). For GEMM1 (NBN==24): 4x4 supertiles
  // within the chunk (working set ~2MB < 4MB per-XCD L2).
  const int xcd = blockIdx.x & 7;
  const int c = blockIdx.x >> 3;  // [0, cpx)
  int bm, bn;
  if constexpr (NBN == 24) {
    const int st = c >> 4;          // 0..11 supertiles (2 rows x 6 cols)
    const int im = (c >> 2) & 3, in_ = c & 3;
    bm = xcd * 8 + (st & 1) * 4 + im;
    bn = (st >> 1) * 4 + in_;
  } else {
    const int cpx = gridDim.x >> 3;
    const int wg = xcd * cpx + c;
    bm = wg / NBN; bn = wg % NBN;
  }
  const int m0 = bm * 128, n0 = bn * 128;

  const int w = t >> 6, lane = t & 63;
  const int wr = w >> 1, wc = w & 1;
  const int lr = lane & 15, kg = lane >> 4;

  // staging granules (8 bf16 = 16B); tile = 512 granules; wave w covers
  // [w*128, w*128+128) in two 64-lane instructions.  LDS slot (row, j)
  // holds global (row, j ^ sw(row)) where sw(row) = (row>>1)&3.
  const int g0 = w * 128 + lane;
  const int g1 = g0 + 64;
  const int r0g = g0 >> 2, j0g = (g0 & 3) ^ ((r0g >> 1) & 3);
  const int r1g = g1 >> 2, j1g = (g1 & 3) ^ ((r1g >> 1) & 3);
  const __hip_bfloat16* srcA0 = A + (size_t)(m0 + r0g) * AS + j0g * 8;
  const __hip_bfloat16* srcA1 = A + (size_t)(m0 + r1g) * AS + j1g * 8;
  const __hip_bfloat16* srcB0 = Bt + (size_t)(n0 + r0g) * KD + j0g * 8;
  const __hip_bfloat16* srcB1 = Bt + (size_t)(n0 + r1g) * KD + j1g * 8;
  const int lds0 = w * 128 * 8;        // element offset of wave's region
  const int lds1 = (w * 128 + 64) * 8;

  f32x4 acc[4][4] = {};
  constexpr int steps = KD / 32;

  auto stage = [&](int buf, int kt) {
    const int ko = kt * 32;
    GLOAD16(srcA0 + ko, &As[buf][lds0]);
    GLOAD16(srcA1 + ko, &As[buf][lds1]);
    GLOAD16(srcB0 + ko, &Bs[buf][lds0]);
    GLOAD16(srcB1 + ko, &Bs[buf][lds1]);
  };

  // fragment read offsets (swizzled): row*32 + (kg ^ ((row>>1)&3))*8
  int offA[4], offB[4];
#pragma unroll
  for (int i = 0; i < 4; ++i) {
    int rowA = wr * 64 + i * 16 + lr;
    int rowB = wc * 64 + i * 16 + lr;
    offA[i] = rowA * 32 + (kg ^ ((rowA >> 1) & 3)) * 8;
    offB[i] = rowB * 32 + (kg ^ ((rowB >> 1) & 3)) * 8;
  }

  // prologue: stage tiles 0,1 -> bufs 0,1; wait tile0 (vmcnt(4))
  stage(0, 0);
  stage(1, 1);
  SCHED();
  WAIT_VM4();
  BAR();
  SCHED();

  int cur = 0;
#pragma unroll 1
  for (int kt = 0; kt < steps; ++kt) {
    if (kt + 2 < steps) {
      int nb = cur + 2; if (nb >= 3) nb -= 3;
      stage(nb, kt + 2);
    }
    SCHED();
    const __hip_bfloat16* Ac = As[cur];
    const __hip_bfloat16* Bc = Bs[cur];
    short8 af[4], bfv[4];
#pragma unroll
    for (int mi = 0; mi < 4; ++mi) af[mi] = *(const short8*)&Ac[offA[mi]];
#pragma unroll
    for (int ni = 0; ni < 4; ++ni) bfv[ni] = *(const short8*)&Bc[offB[ni]];
#pragma unroll
    for (int mi = 0; mi < 4; ++mi)
#pragma unroll
      for (int ni = 0; ni < 4; ++ni)
        acc[mi][ni] = __builtin_amdgcn_mfma_f32_16x16x32_bf16(
            af[mi], bfv[ni], acc[mi][ni], 0, 0, 0);
    SCHED();
    if (kt < steps - 2) WAIT_VM4(); else WAIT_VM0();
    BAR();
    SCHED();
    ++cur; if (cur == 3) cur = 0;
  }

  // C/D layout (m89-verified): col = lane&15, row = (lane>>4)*4 + reg
#pragma unroll
  for (int mi = 0; mi < 4; ++mi) {
    int row0 = m0 + wr * 64 + mi * 16 + kg * 4;
#pragma unroll
    for (int ni = 0; ni < 4; ++ni) {
      int col = n0 + wc * 64 + ni * 16 + lr;
      float bv = bias[col];
#pragma unroll
      for (int r = 0; r < 4; ++r)
        store_out(&C[(size_t)(row0 + r) * NOUT + col], acc[mi][ni][r] + bv);
    }
  }
}

// ---------------- Spart[c][b,h] = K_h^T @ V_h over 128 L-rows ------------
__global__ __launch_bounds__(256) void ktv_kernel(
    const __hip_bfloat16* __restrict__ qkv, float* __restrict__ Spart) {
  __shared__ __align__(16) float Ks[64][68];
  __shared__ __align__(16) float Vs[64][68];
  const int bh = blockIdx.x;                 // 0..127
  const int ch = blockIdx.y;                 // 0..7
  const int b = bh >> 4, h = bh & 15;
  const __hip_bfloat16* base = qkv + (size_t)b * 1024 * 3072;
  const int hoff = h * 64;
  const int t = threadIdx.x;
  const int i0 = (t >> 4) * 4;
  const int j0 = (t & 15) * 4;
  const int srow = t >> 2;
  const int sg0 = t & 3;

  f32x4 acc[4] = {};

  for (int c = 0; c < 2; ++c) {
    int l0 = ch * 128 + c * 64;
#pragma unroll
    for (int rep = 0; rep < 2; ++rep) {
      int g = sg0 + rep * 4;
      const __hip_bfloat16* rowp = base + (size_t)(l0 + srow) * 3072;
      short8 kv = *(const short8*)(rowp + 1024 + hoff + g * 8);
      short8 vv = *(const short8*)(rowp + 2048 + hoff + g * 8);
      f32x4 k0, k1, v0, v1;
#pragma unroll
      for (int e = 0; e < 4; ++e) {
        k0[e] = bf2f(kv[e]); k1[e] = bf2f(kv[4 + e]);
        v0[e] = bf2f(vv[e]); v1[e] = bf2f(vv[4 + e]);
      }
      *(f32x4*)&Ks[srow][g * 8] = k0;
      *(f32x4*)&Ks[srow][g * 8 + 4] = k1;
      *(f32x4*)&Vs[srow][g * 8] = v0;
      *(f32x4*)&Vs[srow][g * 8 + 4] = v1;
    }
    __syncthreads();
#pragma unroll 8
    for (int l = 0; l < 64; ++l) {
      f32x4 kq = *(const f32x4*)&Ks[l][i0];
      f32x4 vq = *(const f32x4*)&Vs[l][j0];
#pragma unroll
      for (int ii = 0; ii < 4; ++ii) acc[ii] += kq[ii] * vq;
    }
    __syncthreads();
  }

  float* Sp = Spart + ((size_t)ch * 128 + bh) * 4096;
#pragma unroll
  for (int ii = 0; ii < 4; ++ii)
#pragma unroll
    for (int jj = 0; jj < 4; ++jj)
      Sp[(i0 + ii) * 64 + j0 + jj] = acc[ii][jj];
}

// ---------------- Ut_b[n][h*64+j] = sum_k (S_bh[j][k]/8) w_outT[n][h*64+k]
// grid (128 bh, 2 n-halves) x 256 thr (4 waves, 128 n-rows each).
__global__ __launch_bounds__(256) void ut_kernel(
    const float* __restrict__ Spart, const __hip_bfloat16* __restrict__ w_outT,
    __hip_bfloat16* __restrict__ Ut) {
  __shared__ __align__(16) __hip_bfloat16 Sl[64][72];  // +8 pad
  const int bh = blockIdx.x;
  const int b = bh >> 4, h = bh & 15;
  const int t = threadIdx.x, w = t >> 6, lane = t & 63;
  const int lr = lane & 15, kg = lane >> 4;
  const int nbase = blockIdx.y * 512 + w * 128;

  // stage S_bh: sum 8 partials, scale 1/8, cast bf16
#pragma unroll
  for (int rep = 0; rep < 4; ++rep) {
    int e4 = t + rep * 256;          // f32x4 granule 0..1023
    int row = e4 >> 4, c4 = e4 & 15;
    f32x4 s = {};
#pragma unroll
    for (int c = 0; c < 8; ++c)
      s += *(const f32x4*)&Spart[((size_t)c * 128 + bh) * 4096 + row * 64 + c4 * 4];
    s *= 0.125f;
    __hip_bfloat16* p = &Sl[row][c4 * 4];
    p[0] = __float2bfloat16(s[0]); p[1] = __float2bfloat16(s[1]);
    p[2] = __float2bfloat16(s[2]); p[3] = __float2bfloat16(s[3]);
  }
  __syncthreads();

  const __hip_bfloat16* Ap = w_outT + (size_t)(nbase + lr) * 1024 + h * 64 + kg * 8;
  short8 bF[4][2];
#pragma unroll
  for (int ni = 0; ni < 4; ++ni)
#pragma unroll
    for (int kk = 0; kk < 2; ++kk)
      bF[ni][kk] = *(const short8*)&Sl[ni * 16 + lr][kk * 32 + kg * 8];

  f32x4 acc[8][4] = {};
#pragma unroll
  for (int mi = 0; mi < 8; ++mi) {
#pragma unroll
    for (int kk = 0; kk < 2; ++kk) {
      short8 aF = *(const short8*)(Ap + (size_t)mi * 16 * 1024 + kk * 32);
#pragma unroll
      for (int ni = 0; ni < 4; ++ni)
        acc[mi][ni] = __builtin_amdgcn_mfma_f32_16x16x32_bf16(
            aF, bF[ni][kk], acc[mi][ni], 0, 0, 0);
    }
  }

  __hip_bfloat16* Up = Ut + (size_t)b * 1024 * 1024;
#pragma unroll
  for (int mi = 0; mi < 8; ++mi) {
    int row0 = nbase + mi * 16 + kg * 4;
#pragma unroll
    for (int ni = 0; ni < 4; ++ni) {
      int col = h * 64 + ni * 16 + lr;
#pragma unroll
      for (int r = 0; r < 4; ++r)
        Up[(size_t)(row0 + r) * 1024 + col] = __float2bfloat16(acc[mi][ni][r]);
    }
  }
}

extern "C" void kernel_launch(void* const* d_in, const int* in_sizes, int n_in,
                              void* d_out, int out_size, void* d_ws, size_t ws_size,
                              hipStream_t stream) {
  const float* x = (const float*)d_in[0];
  const float* w_in = (const float*)d_in[1];
  const float* b_in = (const float*)d_in[2];
  const float* w_out = (const float*)d_in[3];
  const float* b_out = (const float*)d_in[4];
  float* out = (float*)d_out;

  char* ws = (char*)d_ws;
  __hip_bfloat16* x_bf = (__hip_bfloat16*)ws;   ws += (size_t)8192 * 1024 * 2;
  __hip_bfloat16* w_inT = (__hip_bfloat16*)ws;  ws += (size_t)3072 * 1024 * 2;
  __hip_bfloat16* w_outT = (__hip_bfloat16*)ws; ws += (size_t)1024 * 1024 * 2;
  __hip_bfloat16* qkv = (__hip_bfloat16*)ws;    ws += (size_t)8192 * 3072 * 2;
  float* Spart = (float*)ws;                    ws += (size_t)8 * 128 * 64 * 64 * 4;
  __hip_bfloat16* Ut = (__hip_bfloat16*)ws;     ws += (size_t)8 * 1024 * 1024 * 2;

  // fused prep: cast x (4096 blocks) + transpose w_in (3072) + w_out (1024)
  prep_kernel<<<8192, 256, 0, stream>>>(x, x_bf, w_in, w_inT, w_out, w_outT);

  // GEMM1: qkv = x @ w_in + b_in  (8192 x 3072, KD=1024) -> bf16
  gemm_bt_kernel<__hip_bfloat16, 1024, 1024, 24, 3072, 0>
      <<<dim3(1536, 1), 256, 0, stream>>>(x_bf, w_inT, b_in, qkv);

  // S partials = Kt V per (b,h) over 128-row chunks
  ktv_kernel<<<dim3(128, 8), 256, 0, stream>>>(qkv, Spart);

  // Ut_b = (S_bh/8 @ Wout_h)^T stacked  -> bf16 (8 x 1024 x 1024)
  ut_kernel<<<dim3(128, 2), 256, 0, stream>>>(Spart, w_outT, Ut);

  // GEMM4': out_b = Q_b @ U_b + b_out  (8 batched 1024x1024, A stride 3072,
  //         Bt batch stride 1024*1024)
  gemm_bt_kernel<float, 1024, 3072, 8, 1024, 1024 * 1024>
      <<<dim3(64, 8), 256, 0, stream>>>(qkv, Ut, b_out, out);
}

// Round 11
// 137.438 us; speedup vs baseline: 1.0151x; 1.0010x over previous
//
#include <hip/hip_runtime.h>
#include <hip/hip_bf16.h>

// Problem constants: B=8, L=1024, D=1024, H=16, K=64
// Reference (bug reproduced): no softmax => linear attention:
//   out_b = Q_b @ U_b + b_out,  U_b[h*64+j, n] = sum_k S_bh[j,k] w_out[h*64+k, n],
//   S_bh = K_h^T V_h / 8.

typedef __attribute__((ext_vector_type(8))) short short8;
typedef __attribute__((ext_vector_type(4))) float f32x4;

static __device__ __forceinline__ short f2bf(float f) {
  __hip_bfloat16 h = __float2bfloat16(f);
  return __builtin_bit_cast(short, h);
}
static __device__ __forceinline__ float bf2f(short s) {
  unsigned int u = ((unsigned int)(unsigned short)s) << 16;
  return __builtin_bit_cast(float, u);
}

#define GLOAD16(src, dst)                                        \
  __builtin_amdgcn_global_load_lds(                              \
      (const __attribute__((address_space(1))) void*)(src),      \
      (__attribute__((address_space(3))) void*)(dst), 16, 0, 0)
#define BAR() __builtin_amdgcn_s_barrier()
#define SCHED() __builtin_amdgcn_sched_barrier(0)
#define WAIT_VM4() asm volatile("s_waitcnt vmcnt(4)" ::: "memory")
#define WAIT_VM0() asm volatile("s_waitcnt vmcnt(0)" ::: "memory")

// ---------------- fused prep: cast x -> bf16, transpose w_in / w_out -----
static __device__ __forceinline__ void transpose_body(
    const float* __restrict__ in, __hip_bfloat16* __restrict__ out,
    int R, int C, int c0, int r0, float tile[32][33]) {
  int tx = threadIdx.x & 31;
  int ty = threadIdx.x >> 5;  // 0..7
#pragma unroll
  for (int i = 0; i < 4; ++i)
    tile[ty + i * 8][tx] = in[(size_t)(r0 + ty + i * 8) * C + c0 + tx];
  __syncthreads();
#pragma unroll
  for (int i = 0; i < 4; ++i)
    out[(size_t)(c0 + ty + i * 8) * R + r0 + tx] =
        __float2bfloat16(tile[tx][ty + i * 8]);
}

__global__ __launch_bounds__(256) void prep_kernel(
    const float* __restrict__ x, __hip_bfloat16* __restrict__ x_bf,
    const float* __restrict__ w_in, __hip_bfloat16* __restrict__ w_inT,
    const float* __restrict__ w_out, __hip_bfloat16* __restrict__ w_outT) {
  __shared__ float tile[32][33];
  const int bx = blockIdx.x;
  if (bx < 4096) {
    size_t i = ((size_t)bx * 256 + threadIdx.x) * 8;
    float4 v0 = *(const float4*)(x + i);
    float4 v1 = *(const float4*)(x + i + 4);
    short8 o;
    o[0] = f2bf(v0.x); o[1] = f2bf(v0.y); o[2] = f2bf(v0.z); o[3] = f2bf(v0.w);
    o[4] = f2bf(v1.x); o[5] = f2bf(v1.y); o[6] = f2bf(v1.z); o[7] = f2bf(v1.w);
    *(short8*)((__hip_bfloat16*)x_bf + i) = o;
  } else if (bx < 4096 + 3072) {
    int b = bx - 4096;  // w_in: 1024 x 3072 -> 96 x 32 tiles
    transpose_body(w_in, w_inT, 1024, 3072, (b % 96) * 32, (b / 96) * 32, tile);
  } else {
    int b = bx - 7168;  // w_out: 1024 x 1024 -> 32 x 32 tiles
    transpose_body(w_out, w_outT, 1024, 1024, (b % 32) * 32, (b / 32) * 32, tile);
  }
}

// ---------------- bf16 MFMA GEMM (R8-best): 3-buf counted-vmcnt + T2 -----
// C(..xNOUT) = A(stride AS) @ Bt(NxKD)^T + bias.  128x128 tile, BK=32,
// 4 waves (2x2), each wave 64x64 = 4x4 frags of 16x16x32.
// Pipeline: stage tile k+2 at top of step k; s_waitcnt vmcnt(4) (tile k+1
// may stay in flight) + raw s_barrier per step.  LDS [128][32] bf16 with
// kg' = kg ^ ((row>>1)&3) XOR swizzle (bank-conflict-free, verified R8:
// SQ_LDS_BANK_CONFLICT == 0); global_load_lds dest linear, SOURCE
// inverse-permuted (m173 / rule #21).  GEMM1 (NBN==24) uses 4x4 supertile
// ordering within each XCD chunk (FETCH 57->41 MB verified R8).
// NOTE (R10 post-mortem): at MfmaUtil 30% / conflicts 0 / depth-2 latency
// cover, the binding resource is LDS read+DMA BW at 0.5 reads/MFMA; all
// lower-economy tiles fail VGPR (>=176) or grid quantization (1.5 rounds).
// This config is the constrained optimum for M=8192/3072, K=1024.
static __device__ __forceinline__ void store_out(__hip_bfloat16* p, float v) {
  *p = __float2bfloat16(v);
}
static __device__ __forceinline__ void store_out(float* p, float v) { *p = v; }

template <typename OutT, int KD, int AS, int NBN, int NOUT, long BTB>
__global__ __launch_bounds__(256) void gemm_bt_kernel(
    const __hip_bfloat16* __restrict__ A, const __hip_bfloat16* __restrict__ Bt,
    const float* __restrict__ bias, OutT* __restrict__ C) {
  __shared__ __align__(16) __hip_bfloat16 As[3][128 * 32];
  __shared__ __align__(16) __hip_bfloat16 Bs[3][128 * 32];

  const int t = threadIdx.x;
  A += (size_t)blockIdx.y * 1024 * AS;
  Bt += (size_t)blockIdx.y * BTB;
  C += (size_t)blockIdx.y * 1024 * NOUT;

  // XCD swizzle (gridDim.x % 8 == 0). For GEMM1 (NBN==24): 4x4 supertiles
  // within the chunk (working set ~2MB < 4MB per-XCD L2).
  const int xcd = blockIdx.x & 7;
  const int c = blockIdx.x >> 3;  // [0, cpx)
  int bm, bn;
  if constexpr (NBN == 24) {
    const int st = c >> 4;          // 0..11 supertiles (2 rows x 6 cols)
    const int im = (c >> 2) & 3, in_ = c & 3;
    bm = xcd * 8 + (st & 1) * 4 + im;
    bn = (st >> 1) * 4 + in_;
  } else {
    const int cpx = gridDim.x >> 3;
    const int wg = xcd * cpx + c;
    bm = wg / NBN; bn = wg % NBN;
  }
  const int m0 = bm * 128, n0 = bn * 128;

  const int w = t >> 6, lane = t & 63;
  const int wr = w >> 1, wc = w & 1;
  const int lr = lane & 15, kg = lane >> 4;

  // staging granules (8 bf16 = 16B); tile = 512 granules; wave w covers
  // [w*128, w*128+128) in two 64-lane instructions.  LDS slot (row, j)
  // holds global (row, j ^ sw(row)) where sw(row) = (row>>1)&3.
  const int g0 = w * 128 + lane;
  const int g1 = g0 + 64;
  const int r0g = g0 >> 2, j0g = (g0 & 3) ^ ((r0g >> 1) & 3);
  const int r1g = g1 >> 2, j1g = (g1 & 3) ^ ((r1g >> 1) & 3);
  const __hip_bfloat16* srcA0 = A + (size_t)(m0 + r0g) * AS + j0g * 8;
  const __hip_bfloat16* srcA1 = A + (size_t)(m0 + r1g) * AS + j1g * 8;
  const __hip_bfloat16* srcB0 = Bt + (size_t)(n0 + r0g) * KD + j0g * 8;
  const __hip_bfloat16* srcB1 = Bt + (size_t)(n0 + r1g) * KD + j1g * 8;
  const int lds0 = w * 128 * 8;        // element offset of wave's region
  const int lds1 = (w * 128 + 64) * 8;

  f32x4 acc[4][4] = {};
  constexpr int steps = KD / 32;

  auto stage = [&](int buf, int kt) {
    const int ko = kt * 32;
    GLOAD16(srcA0 + ko, &As[buf][lds0]);
    GLOAD16(srcA1 + ko, &As[buf][lds1]);
    GLOAD16(srcB0 + ko, &Bs[buf][lds0]);
    GLOAD16(srcB1 + ko, &Bs[buf][lds1]);
  };

  // fragment read offsets (swizzled): row*32 + (kg ^ ((row>>1)&3))*8
  int offA[4], offB[4];
#pragma unroll
  for (int i = 0; i < 4; ++i) {
    int rowA = wr * 64 + i * 16 + lr;
    int rowB = wc * 64 + i * 16 + lr;
    offA[i] = rowA * 32 + (kg ^ ((rowA >> 1) & 3)) * 8;
    offB[i] = rowB * 32 + (kg ^ ((rowB >> 1) & 3)) * 8;
  }

  // prologue: stage tiles 0,1 -> bufs 0,1; wait tile0 (vmcnt(4))
  stage(0, 0);
  stage(1, 1);
  SCHED();
  WAIT_VM4();
  BAR();
  SCHED();

  int cur = 0;
#pragma unroll 1
  for (int kt = 0; kt < steps; ++kt) {
    if (kt + 2 < steps) {
      int nb = cur + 2; if (nb >= 3) nb -= 3;
      stage(nb, kt + 2);
    }
    SCHED();
    const __hip_bfloat16* Ac = As[cur];
    const __hip_bfloat16* Bc = Bs[cur];
    short8 af[4], bfv[4];
#pragma unroll
    for (int mi = 0; mi < 4; ++mi) af[mi] = *(const short8*)&Ac[offA[mi]];
#pragma unroll
    for (int ni = 0; ni < 4; ++ni) bfv[ni] = *(const short8*)&Bc[offB[ni]];
#pragma unroll
    for (int mi = 0; mi < 4; ++mi)
#pragma unroll
      for (int ni = 0; ni < 4; ++ni)
        acc[mi][ni] = __builtin_amdgcn_mfma_f32_16x16x32_bf16(
            af[mi], bfv[ni], acc[mi][ni], 0, 0, 0);
    SCHED();
    if (kt < steps - 2) WAIT_VM4(); else WAIT_VM0();
    BAR();
    SCHED();
    ++cur; if (cur == 3) cur = 0;
  }

  // C/D layout (m89-verified): col = lane&15, row = (lane>>4)*4 + reg
#pragma unroll
  for (int mi = 0; mi < 4; ++mi) {
    int row0 = m0 + wr * 64 + mi * 16 + kg * 4;
#pragma unroll
    for (int ni = 0; ni < 4; ++ni) {
      int col = n0 + wc * 64 + ni * 16 + lr;
      float bv = bias[col];
#pragma unroll
      for (int r = 0; r < 4; ++r)
        store_out(&C[(size_t)(row0 + r) * NOUT + col], acc[mi][ni][r] + bv);
    }
  }
}

// ---------------- Spart[c][b,h] = K_h^T @ V_h over 256 L-rows ------------
// grid (128 bh, 4 chunks); 512 blocks = exactly 2/CU.  Partials fp32,
// summed by ut_kernel (Spart 8 MB vs 16 MB at 8 chunks).
__global__ __launch_bounds__(256) void ktv_kernel(
    const __hip_bfloat16* __restrict__ qkv, float* __restrict__ Spart) {
  __shared__ __align__(16) float Ks[64][68];
  __shared__ __align__(16) float Vs[64][68];
  const int bh = blockIdx.x;                 // 0..127
  const int ch = blockIdx.y;                 // 0..3
  const int b = bh >> 4, h = bh & 15;
  const __hip_bfloat16* base = qkv + (size_t)b * 1024 * 3072;
  const int hoff = h * 64;
  const int t = threadIdx.x;
  const int i0 = (t >> 4) * 4;
  const int j0 = (t & 15) * 4;
  const int srow = t >> 2;
  const int sg0 = t & 3;

  f32x4 acc[4] = {};

  for (int c = 0; c < 4; ++c) {
    int l0 = ch * 256 + c * 64;
#pragma unroll
    for (int rep = 0; rep < 2; ++rep) {
      int g = sg0 + rep * 4;
      const __hip_bfloat16* rowp = base + (size_t)(l0 + srow) * 3072;
      short8 kv = *(const short8*)(rowp + 1024 + hoff + g * 8);
      short8 vv = *(const short8*)(rowp + 2048 + hoff + g * 8);
      f32x4 k0, k1, v0, v1;
#pragma unroll
      for (int e = 0; e < 4; ++e) {
        k0[e] = bf2f(kv[e]); k1[e] = bf2f(kv[4 + e]);
        v0[e] = bf2f(vv[e]); v1[e] = bf2f(vv[4 + e]);
      }
      *(f32x4*)&Ks[srow][g * 8] = k0;
      *(f32x4*)&Ks[srow][g * 8 + 4] = k1;
      *(f32x4*)&Vs[srow][g * 8] = v0;
      *(f32x4*)&Vs[srow][g * 8 + 4] = v1;
    }
    __syncthreads();
#pragma unroll 8
    for (int l = 0; l < 64; ++l) {
      f32x4 kq = *(const f32x4*)&Ks[l][i0];
      f32x4 vq = *(const f32x4*)&Vs[l][j0];
#pragma unroll
      for (int ii = 0; ii < 4; ++ii) acc[ii] += kq[ii] * vq;
    }
    __syncthreads();
  }

  float* Sp = Spart + ((size_t)ch * 128 + bh) * 4096;
#pragma unroll
  for (int ii = 0; ii < 4; ++ii)
#pragma unroll
    for (int jj = 0; jj < 4; ++jj)
      Sp[(i0 + ii) * 64 + j0 + jj] = acc[ii][jj];
}

// ---------------- Ut_b[n][h*64+j] = sum_k (S_bh[j][k]/8) w_outT[n][h*64+k]
// grid (128 bh, 2 n-halves) x 256 thr (4 waves, 128 n-rows each).
__global__ __launch_bounds__(256) void ut_kernel(
    const float* __restrict__ Spart, const __hip_bfloat16* __restrict__ w_outT,
    __hip_bfloat16* __restrict__ Ut) {
  __shared__ __align__(16) __hip_bfloat16 Sl[64][72];  // +8 pad
  const int bh = blockIdx.x;
  const int b = bh >> 4, h = bh & 15;
  const int t = threadIdx.x, w = t >> 6, lane = t & 63;
  const int lr = lane & 15, kg = lane >> 4;
  const int nbase = blockIdx.y * 512 + w * 128;

  // stage S_bh: sum 4 partials, scale 1/8, cast bf16
#pragma unroll
  for (int rep = 0; rep < 4; ++rep) {
    int e4 = t + rep * 256;          // f32x4 granule 0..1023
    int row = e4 >> 4, c4 = e4 & 15;
    f32x4 s = {};
#pragma unroll
    for (int c = 0; c < 4; ++c)
      s += *(const f32x4*)&Spart[((size_t)c * 128 + bh) * 4096 + row * 64 + c4 * 4];
    s *= 0.125f;
    __hip_bfloat16* p = &Sl[row][c4 * 4];
    p[0] = __float2bfloat16(s[0]); p[1] = __float2bfloat16(s[1]);
    p[2] = __float2bfloat16(s[2]); p[3] = __float2bfloat16(s[3]);
  }
  __syncthreads();

  const __hip_bfloat16* Ap = w_outT + (size_t)(nbase + lr) * 1024 + h * 64 + kg * 8;
  short8 bF[4][2];
#pragma unroll
  for (int ni = 0; ni < 4; ++ni)
#pragma unroll
    for (int kk = 0; kk < 2; ++kk)
      bF[ni][kk] = *(const short8*)&Sl[ni * 16 + lr][kk * 32 + kg * 8];

  f32x4 acc[8][4] = {};
#pragma unroll
  for (int mi = 0; mi < 8; ++mi) {
#pragma unroll
    for (int kk = 0; kk < 2; ++kk) {
      short8 aF = *(const short8*)(Ap + (size_t)mi * 16 * 1024 + kk * 32);
#pragma unroll
      for (int ni = 0; ni < 4; ++ni)
        acc[mi][ni] = __builtin_amdgcn_mfma_f32_16x16x32_bf16(
            aF, bF[ni][kk], acc[mi][ni], 0, 0, 0);
    }
  }

  __hip_bfloat16* Up = Ut + (size_t)b * 1024 * 1024;
#pragma unroll
  for (int mi = 0; mi < 8; ++mi) {
    int row0 = nbase + mi * 16 + kg * 4;
#pragma unroll
    for (int ni = 0; ni < 4; ++ni) {
      int col = h * 64 + ni * 16 + lr;
#pragma unroll
      for (int r = 0; r < 4; ++r)
        Up[(size_t)(row0 + r) * 1024 + col] = __float2bfloat16(acc[mi][ni][r]);
    }
  }
}

extern "C" void kernel_launch(void* const* d_in, const int* in_sizes, int n_in,
                              void* d_out, int out_size, void* d_ws, size_t ws_size,
                              hipStream_t stream) {
  const float* x = (const float*)d_in[0];
  const float* w_in = (const float*)d_in[1];
  const float* b_in = (const float*)d_in[2];
  const float* w_out = (const float*)d_in[3];
  const float* b_out = (const float*)d_in[4];
  float* out = (float*)d_out;

  char* ws = (char*)d_ws;
  __hip_bfloat16* x_bf = (__hip_bfloat16*)ws;   ws += (size_t)8192 * 1024 * 2;
  __hip_bfloat16* w_inT = (__hip_bfloat16*)ws;  ws += (size_t)3072 * 1024 * 2;
  __hip_bfloat16* w_outT = (__hip_bfloat16*)ws; ws += (size_t)1024 * 1024 * 2;
  __hip_bfloat16* qkv = (__hip_bfloat16*)ws;    ws += (size_t)8192 * 3072 * 2;
  float* Spart = (float*)ws;                    ws += (size_t)4 * 128 * 64 * 64 * 4;
  __hip_bfloat16* Ut = (__hip_bfloat16*)ws;     ws += (size_t)8 * 1024 * 1024 * 2;

  // fused prep: cast x (4096 blocks) + transpose w_in (3072) + w_out (1024)
  prep_kernel<<<8192, 256, 0, stream>>>(x, x_bf, w_in, w_inT, w_out, w_outT);

  // GEMM1: qkv = x @ w_in + b_in  (8192 x 3072, KD=1024) -> bf16
  gemm_bt_kernel<__hip_bfloat16, 1024, 1024, 24, 3072, 0>
      <<<dim3(1536, 1), 256, 0, stream>>>(x_bf, w_inT, b_in, qkv);

  // S partials = Kt V per (b,h) over 256-row chunks (512 blocks = 2/CU)
  ktv_kernel<<<dim3(128, 4), 256, 0, stream>>>(qkv, Spart);

  // Ut_b = (S_bh/8 @ Wout_h)^T stacked  -> bf16 (8 x 1024 x 1024)
  ut_kernel<<<dim3(128, 2), 256, 0, stream>>>(Spart, w_outT, Ut);

  // GEMM4': out_b = Q_b @ U_b + b_out  (8 batched 1024x1024, A stride 3072,
  //         Bt batch stride 1024*1024)
  gemm_bt_kernel<float, 1024, 3072, 8, 1024, 1024 * 1024>
      <<<dim3(64, 8), 256, 0, stream>>>(qkv, Ut, b_out, out);
}